// Round 1
// baseline (1507.917 us; speedup 1.0000x reference)
//
#include <hip/hip_runtime.h>

#define C 64

__global__ void deg_kernel(const int* __restrict__ row, float* __restrict__ deg, int ne) {
    int i = blockIdx.x * blockDim.x + threadIdx.x;
    int stride = gridDim.x * blockDim.x;
    for (; i < ne; i += stride) atomicAdd(&deg[row[i]], 1.0f);
}

__global__ void dis_kernel(float* __restrict__ deg, int bn) {
    int i = blockIdx.x * blockDim.x + threadIdx.x;
    if (i < bn) {
        float d = deg[i];
        deg[i] = d > 0.0f ? rsqrtf(d) : 0.0f;
    }
}

__global__ void linear_kernel(const float* __restrict__ x, const float* __restrict__ W,
                              const float* __restrict__ b, float* __restrict__ h, int bn) {
    __shared__ float Ws[64][64];   // Ws[k][c]
    __shared__ float bs[64];
    for (int i = threadIdx.x; i < 64 * 64; i += blockDim.x) Ws[i >> 6][i & 63] = W[i];
    if (threadIdx.x < 64) bs[threadIdx.x] = b[threadIdx.x];
    __syncthreads();
    const int c = threadIdx.x & 63;      // output channel
    const int rloc = threadIdx.x >> 6;   // 0..3 (256 threads -> 4 rows per iter)
    for (int rbase = blockIdx.x * 4; rbase < bn; rbase += gridDim.x * 4) {
        int r = rbase + rloc;
        if (r >= bn) break;
        const float* xr = x + (size_t)r * C;
        float acc = bs[c];
#pragma unroll
        for (int k = 0; k < 64; k += 4) {
            float4 xv = *reinterpret_cast<const float4*>(xr + k);
            acc = fmaf(xv.x, Ws[k][c], acc);
            acc = fmaf(xv.y, Ws[k + 1][c], acc);
            acc = fmaf(xv.z, Ws[k + 2][c], acc);
            acc = fmaf(xv.w, Ws[k + 3][c], acc);
        }
        h[(size_t)r * C + c] = acc;
    }
}

// 16 threads per edge; each thread handles 4 contiguous channels (float4 gather,
// 4 scalar float atomics into the destination row).
__global__ void scatter_kernel(const int* __restrict__ row, const int* __restrict__ col,
                               const float* __restrict__ dis, const float* __restrict__ h,
                               float* __restrict__ y, int ne) {
    int idx = blockIdx.x * blockDim.x + threadIdx.x;  // over ne*16
    if (idx >= ne * 16) return;
    int e = idx >> 4;
    int c4 = (idx & 15) << 2;
    int r = row[e];
    int d = col[e];
    float norm = dis[r] * dis[d];
    const float4 hv = *reinterpret_cast<const float4*>(h + (size_t)r * C + c4);
    float* yp = y + (size_t)d * C + c4;
    atomicAdd(yp + 0, norm * hv.x);
    atomicAdd(yp + 1, norm * hv.y);
    atomicAdd(yp + 2, norm * hv.z);
    atomicAdd(yp + 3, norm * hv.w);
}

extern "C" void kernel_launch(void* const* d_in, const int* in_sizes, int n_in,
                              void* d_out, int out_size, void* d_ws, size_t ws_size,
                              hipStream_t stream) {
    const float* x = (const float*)d_in[0];
    const int*   e = (const int*)d_in[1];
    const float* W = (const float*)d_in[2];
    const float* b = (const float*)d_in[3];
    float* y = (float*)d_out;

    const int bn = in_sizes[0] / C;   // 100000
    const int ne = in_sizes[1] / 2;   // 1600000

    const int* rowi = e;
    const int* coli = e + ne;

    float* deg = (float*)d_ws;                                     // bn floats (becomes deg^{-1/2})
    float* h   = (float*)((char*)d_ws + (size_t)bn * sizeof(float)); // bn*64 floats

    // accumulation buffers must start at zero every call
    hipMemsetAsync(deg, 0, (size_t)bn * sizeof(float), stream);
    hipMemsetAsync(y, 0, (size_t)bn * C * sizeof(float), stream);

    deg_kernel<<<2048, 256, 0, stream>>>(rowi, deg, ne);
    dis_kernel<<<(bn + 255) / 256, 256, 0, stream>>>(deg, bn);
    linear_kernel<<<2048, 256, 0, stream>>>(x, W, b, h, bn);

    int scatter_items = ne * 16;
    scatter_kernel<<<(scatter_items + 255) / 256, 256, 0, stream>>>(rowi, coli, deg, h, y, ne);
}

// Round 2
// 504.847 us; speedup vs baseline: 2.9869x; 2.9869x over previous
//
#include <hip/hip_runtime.h>

#define C 64

// Histogram both endpoints: degr = bincount(row) (for norm), cntc = bincount(col) (CSR buckets)
__global__ void hist_kernel(const int* __restrict__ row, const int* __restrict__ col,
                            int* __restrict__ degr, int* __restrict__ cntc, int ne) {
    int i = blockIdx.x * blockDim.x + threadIdx.x;
    int stride = gridDim.x * blockDim.x;
    for (; i < ne; i += stride) {
        atomicAdd(&degr[row[i]], 1);
        atomicAdd(&cntc[col[i]], 1);
    }
}

// In-place: int degree count -> float deg^{-1/2}
__global__ void dis_kernel(int* __restrict__ degr, int bn) {
    int i = blockIdx.x * blockDim.x + threadIdx.x;
    if (i < bn) {
        int d = degr[i];
        float v = d > 0 ? rsqrtf((float)d) : 0.0f;
        ((float*)degr)[i] = v;
    }
}

// Single-block exclusive scan of cntc (bn elems) -> offs[bn+1]; also copy into cursor.
__global__ __launch_bounds__(1024) void scan_kernel(const int* __restrict__ cnt,
                                                    int* __restrict__ offs,
                                                    int* __restrict__ cursor, int bn) {
    __shared__ int wsum[16];
    __shared__ int s_carry;
    const int lane = threadIdx.x & 63;
    const int wid = threadIdx.x >> 6;
    if (threadIdx.x == 0) s_carry = 0;
    __syncthreads();
    for (int base = 0; base < bn; base += 1024) {
        int i = base + (int)threadIdx.x;
        int v = (i < bn) ? cnt[i] : 0;
        // wave inclusive scan
        int x = v;
#pragma unroll
        for (int off = 1; off < 64; off <<= 1) {
            int t = __shfl_up(x, off, 64);
            if (lane >= off) x += t;
        }
        if (lane == 63) wsum[wid] = x;
        __syncthreads();
        if (wid == 0) {
            int ws = (lane < 16) ? wsum[lane] : 0;
            int y2 = ws;
#pragma unroll
            for (int off = 1; off < 16; off <<= 1) {
                int t = __shfl_up(y2, off, 64);
                if (lane >= off) y2 += t;
            }
            if (lane < 16) wsum[lane] = y2 - ws;  // exclusive offset of wave `lane`
        }
        __syncthreads();
        int incl = x + wsum[wid] + s_carry;
        int excl = incl - v;
        if (i < bn) { offs[i] = excl; cursor[i] = excl; }
        __syncthreads();  // everyone done reading s_carry
        if (threadIdx.x == 1023) s_carry = incl;  // chunk total + old carry
        __syncthreads();
    }
    if (threadIdx.x == 0) offs[bn] = s_carry;
}

// Bucket edges by destination: srcs[] holds source node ids grouped by dst.
__global__ void reorder_kernel(const int* __restrict__ row, const int* __restrict__ col,
                               int* __restrict__ cursor, int* __restrict__ srcs, int ne) {
    int i = blockIdx.x * blockDim.x + threadIdx.x;
    int stride = gridDim.x * blockDim.x;
    for (; i < ne; i += stride) {
        int pos = atomicAdd(&cursor[col[i]], 1);
        srcs[pos] = row[i];
    }
}

__global__ void linear_kernel(const float* __restrict__ x, const float* __restrict__ W,
                              const float* __restrict__ b, float* __restrict__ h, int bn) {
    __shared__ float Ws[64][64];   // Ws[k][c]
    __shared__ float bs[64];
    for (int i = threadIdx.x; i < 64 * 64; i += blockDim.x) Ws[i >> 6][i & 63] = W[i];
    if (threadIdx.x < 64) bs[threadIdx.x] = b[threadIdx.x];
    __syncthreads();
    const int c = threadIdx.x & 63;
    const int rloc = threadIdx.x >> 6;
    for (int rbase = blockIdx.x * 4; rbase < bn; rbase += gridDim.x * 4) {
        int r = rbase + rloc;
        if (r >= bn) break;
        const float* xr = x + (size_t)r * C;
        float acc = bs[c];
#pragma unroll
        for (int k = 0; k < 64; k += 4) {
            float4 xv = *reinterpret_cast<const float4*>(xr + k);
            acc = fmaf(xv.x, Ws[k][c], acc);
            acc = fmaf(xv.y, Ws[k + 1][c], acc);
            acc = fmaf(xv.z, Ws[k + 2][c], acc);
            acc = fmaf(xv.w, Ws[k + 3][c], acc);
        }
        h[(size_t)r * C + c] = acc;
    }
}

// One wave per destination row; lane = channel. No atomics.
__global__ void gather_kernel(const int* __restrict__ offs, const int* __restrict__ srcs,
                              const float* __restrict__ dis, const float* __restrict__ h,
                              float* __restrict__ y, int bn) {
    int r = blockIdx.x * (blockDim.x >> 6) + (threadIdx.x >> 6);
    if (r >= bn) return;
    const int lane = threadIdx.x & 63;
    const int s0 = offs[r], e0 = offs[r + 1];
    float acc = 0.0f;
    int j = s0;
    for (; j + 4 <= e0; j += 4) {
        int a = srcs[j], b2 = srcs[j + 1], c2 = srcs[j + 2], d2 = srcs[j + 3];
        float da = dis[a], db = dis[b2], dc = dis[c2], dd = dis[d2];
        float ha = h[(size_t)a * C + lane];
        float hb = h[(size_t)b2 * C + lane];
        float hc = h[(size_t)c2 * C + lane];
        float hd = h[(size_t)d2 * C + lane];
        acc = fmaf(da, ha, acc);
        acc = fmaf(db, hb, acc);
        acc = fmaf(dc, hc, acc);
        acc = fmaf(dd, hd, acc);
    }
    for (; j < e0; ++j) {
        int a = srcs[j];
        acc = fmaf(dis[a], h[(size_t)a * C + lane], acc);
    }
    y[(size_t)r * C + lane] = acc * dis[r];
}

extern "C" void kernel_launch(void* const* d_in, const int* in_sizes, int n_in,
                              void* d_out, int out_size, void* d_ws, size_t ws_size,
                              hipStream_t stream) {
    const float* x = (const float*)d_in[0];
    const int*   e = (const int*)d_in[1];
    const float* W = (const float*)d_in[2];
    const float* b = (const float*)d_in[3];
    float* y = (float*)d_out;

    const int bn = in_sizes[0] / C;   // 100000
    const int ne = in_sizes[1] / 2;   // 1600000

    const int* rowi = e;
    const int* coli = e + ne;

    // Workspace layout (16B-aligned chunks):
    char* ws = (char*)d_ws;
    int*   degr   = (int*)ws;                    ws += (size_t)bn * 4;        // -> becomes dis (float)
    int*   cntc   = (int*)ws;                    ws += (size_t)bn * 4;
    int*   offs   = (int*)ws;                    ws += ((size_t)bn + 4) * 4;  // bn+1 used, padded
    int*   cursor = (int*)ws;                    ws += (size_t)bn * 4;
    int*   srcs   = (int*)ws;                    ws += (size_t)ne * 4;
    float* h      = (float*)ws;                  // bn*64 floats

    hipMemsetAsync(degr, 0, (size_t)bn * 4, stream);
    hipMemsetAsync(cntc, 0, (size_t)bn * 4, stream);

    hist_kernel<<<2048, 256, 0, stream>>>(rowi, coli, degr, cntc, ne);
    dis_kernel<<<(bn + 255) / 256, 256, 0, stream>>>(degr, bn);
    scan_kernel<<<1, 1024, 0, stream>>>(cntc, offs, cursor, bn);
    reorder_kernel<<<2048, 256, 0, stream>>>(rowi, coli, cursor, srcs, ne);
    linear_kernel<<<2048, 256, 0, stream>>>(x, W, b, h, bn);

    const float* dis = (const float*)degr;
    gather_kernel<<<(bn + 3) / 4, 256, 0, stream>>>(offs, srcs, dis, h, y, bn);
}